// Round 10
// baseline (766.748 us; speedup 1.0000x reference)
//
#include <hip/hip_runtime.h>
#include <hip/hip_cooperative_groups.h>
namespace cg = cooperative_groups;

#define NN 50000
#define E0 800000
#define ET 850000          // E0 + NN self loops
#define EPS_BN 1e-5f
#define SLOPE 0.2f
#define NBP 32             // bn partial blocks
#define TPB 512
#define GRID 256
#define EPC 3328           // edges per chunk
#define NCH 256            // ceil(ET/EPC) == GRID
#define PBITS 8
#define PSZ 256            // dst per partition
#define NP 196             // ceil(NN/256)
#define SCN (NP*NCH)       // 50176 scan elements (partition-major)
#define PERB 196           // SCN / GRID exactly

__device__ __forceinline__ float lrelu(float v){ return v > 0.f ? v : SLOPE*v; }

struct Args {
  const float* x; const int* ei;
  const float* gamma; const float* beta;
  const float* w_e1; const float* as_e1; const float* ad_e1; const float* b_e1;
  const float* w_e3; const float* as_e3; const float* ad_e3; const float* b_e3;
  const float* w_d1; const float* as_d1; const float* ad_d1; const float* b_d1;
  const float* w_d3; const float* as_d3; const float* ad_d3; const float* b_d3;
  int* chunkcnt; int* bsum; int* bofs; int* pofs;
  unsigned int* pedge; int* rowptr; unsigned short* ssrc;
  float* part; float* sclsft; float* fold;
  float2* pk2; float2* lat2; float4* pk4; float* out;
};

__global__ __launch_bounds__(TPB, 2) void fused(Args a){
  cg::grid_group gg = cg::this_grid();
  __shared__ int sh[512];
  __shared__ float bnlds[64];
  const int b = blockIdx.x, t = threadIdx.x;

  // ================= P1: per-chunk partition histogram + BN partials =================
  {
    for (int i=t;i<NP;i+=TPB) sh[i]=0;
    __syncthreads();
    int base=b*EPC, end=min(base+EPC,ET);
    for (int e=base+t; e<end; e+=TPB){
      int dst = (e<E0) ? a.ei[E0+e] : (e-E0);
      atomicAdd(&sh[dst>>PBITS],1);
    }
    __syncthreads();
    for (int i=t;i<NP;i+=TPB) a.chunkcnt[b*NP+i]=sh[i];
  }
  if (b < NBP){
    float s[4]={0,0,0,0}, q[4]={0,0,0,0};
    for (int n=b*TPB+t; n<NN; n+=NBP*TPB){
      float4 v = reinterpret_cast<const float4*>(a.x)[n];
      s[0]+=v.x; s[1]+=v.y; s[2]+=v.z; s[3]+=v.w;
      q[0]+=v.x*v.x; q[1]+=v.y*v.y; q[2]+=v.z*v.z; q[3]+=v.w*v.w;
    }
    #pragma unroll
    for (int m=1;m<64;m<<=1){
      #pragma unroll
      for (int i=0;i<4;i++){ s[i]+=__shfl_xor(s[i],m); q[i]+=__shfl_xor(q[i],m); }
    }
    int wid=t>>6, lane=t&63;
    if (lane==0){
      #pragma unroll
      for (int i=0;i<4;i++){ bnlds[wid*8+i]=s[i]; bnlds[wid*8+4+i]=q[i]; }
    }
    __syncthreads();
    if (t<8){
      float p = 0.f;
      #pragma unroll
      for (int w=0;w<8;w++) p += bnlds[w*8+t];
      a.part[b*8+t]=p;
    }
  }
  __threadfence(); gg.sync();

  // ================= P2a: per-block segment sums (partition-major order) =================
  {
    int mysum=0;
    if (t<PERB){
      int g=b*PERB+t; int p=g>>8, ch=g&(NCH-1);   // NCH=256
      mysum = a.chunkcnt[ch*NP+p];
    }
    // note: g>>8 == g/NCH only because PERB*GRID==SCN and NCH==256
    sh[t]=mysum; __syncthreads();
    for (int off=256;off>=1;off>>=1){ if (t<off) sh[t]+=sh[t+off]; __syncthreads(); }
    if (t==0) a.bsum[b]=sh[0];
  }
  __threadfence(); gg.sync();

  // ================= P2b: block0 scans bsum; block1 BN finalize; block2 fold =================
  if (b==0){
    int v=(t<GRID)? a.bsum[t] : 0;
    sh[t]=v; __syncthreads();
    for (int off=1;off<GRID;off<<=1){
      int tmp=(t>=off)?sh[t-off]:0; __syncthreads();
      sh[t]+=tmp; __syncthreads();
    }
    if (t<GRID) a.bofs[t]=sh[t]-v;
  } else if (b==1){
    if (t<64){
      int ch=t&7, bslot=t>>3;
      float s=0.f;
      for (int bb=bslot; bb<NBP; bb+=8) s += a.part[bb*8+ch];
      s += __shfl_xor(s,8); s += __shfl_xor(s,16); s += __shfl_xor(s,32);
      float qv = __shfl(s,(t&3)+4);
      if (t<4){
        float mu  = s*(1.0f/NN);
        float var = qv*(1.0f/NN) - mu*mu;
        float scl = rsqrtf(var + EPS_BN)*a.gamma[t];
        a.sclsft[t]   = scl;
        a.sclsft[4+t] = a.beta[t] - mu*scl;
      }
    }
  } else if (b==2){
    if (t<32){
      int idx=t&15; int h=idx>>2; int i=idx&3;
      const float* aa = (t<16) ? a.as_e1 : a.ad_e1;
      float sum=0.f;
      for (int c=0;c<32;c++) sum += a.w_e1[i*128+h*32+c]*aa[h*32+c];
      a.fold[t]=sum;
    } else if (t<48){
      int idx=t-32; int j=idx&7; int h=j>>1; int i=j&1;
      const float* aa = (idx<8) ? a.as_d1 : a.ad_d1;
      float sum=0.f;
      for (int c=0;c<32;c++) sum += a.w_d1[i*128+h*32+c]*aa[h*32+c];
      a.fold[32+idx]=sum;
    }
  }
  __threadfence(); gg.sync();

  // ================= P2c: per-block exclusive scan of its segment -> pofs =================
  {
    int v=0;
    if (t<PERB){
      int g=b*PERB+t; int p=g>>8, ch=g&(NCH-1);
      v = a.chunkcnt[ch*NP+p];
    }
    sh[t]=v; __syncthreads();
    for (int off=1;off<256;off<<=1){
      int tmp=(t>=off)?sh[t-off]:0; __syncthreads();
      sh[t]+=tmp; __syncthreads();
    }
    if (t<PERB){
      int g=b*PERB+t; int p=g>>8, ch=g&(NCH-1);
      a.pofs[ch*NP+p] = a.bofs[b] + sh[t] - v;
    }
  }
  __threadfence(); gg.sync();

  // ================= P3: partition pass (chunk-exclusive runs, packed 4B edges) =================
  {
    for (int i=t;i<NP;i+=TPB) sh[i]=a.pofs[b*NP+i];
    __syncthreads();
    int base=b*EPC, end=min(base+EPC,ET);
    for (int e=base+t; e<end; e+=TPB){
      int src,dst;
      if (e<E0){ src=a.ei[e]; dst=a.ei[E0+e]; } else { src=dst=e-E0; }
      int pos=atomicAdd(&sh[dst>>PBITS],1);
      a.pedge[pos] = ((unsigned)src<<PBITS) | (unsigned)(dst&(PSZ-1));
    }
  }
  __threadfence(); gg.sync();

  // ================= P4: fine build -> rowptr + ssrc (uint16) =================
  if (b < NP){
    int pstart=a.pofs[b];                     // pofs[0*NP+b] = partition start
    int pend=(b+1<NP)? a.pofs[b+1] : ET;
    int dbase=b<<PBITS;
    if (t<PSZ) sh[t]=0;
    __syncthreads();
    for (int i=pstart+t;i<pend;i+=TPB) atomicAdd(&sh[a.pedge[i]&(PSZ-1)],1);
    __syncthreads();
    int o=(t<PSZ)?sh[t]:0;
    __syncthreads();
    for (int off=1;off<PSZ;off<<=1){
      int tmp=(t>=off&&t<PSZ)?sh[t-off]:0; __syncthreads();
      if (t<PSZ) sh[t]+=tmp;
      __syncthreads();
    }
    if (t<PSZ){
      int excl=sh[t]-o;
      int d=dbase+t;
      if (d<NN) a.rowptr[d]=pstart+excl;
      sh[PSZ+t]=pstart+excl;
    }
    if (b==NP-1 && t==0) a.rowptr[NN]=ET;
    __syncthreads();
    for (int i=pstart+t;i<pend;i+=TPB){
      unsigned e=a.pedge[i];
      int pos=atomicAdd(&sh[PSZ+(int)(e&(PSZ-1))],1);
      a.ssrc[pos]=(unsigned short)(e>>PBITS);
    }
  }
  __threadfence(); gg.sync();

  // ================= P5: eagg1 (BN+scores per edge) + fused post1 =================
  {
    float sc[8];
    #pragma unroll
    for (int i=0;i<8;i++) sc[i]=a.sclsft[i];
    float fs[16];
    #pragma unroll
    for (int i=0;i<16;i++) fs[i]=a.fold[i];
    float fd[16];
    #pragma unroll
    for (int i=0;i<16;i++) fd[i]=a.fold[16+i];
    int sub=t&3;
    for (int dst=b*128+(t>>2); dst<NN; dst+=GRID*128){
      float4 xd=reinterpret_cast<const float4*>(a.x)[dst];
      float xbd[4]={xd.x*sc[0]+sc[4], xd.y*sc[1]+sc[5], xd.z*sc[2]+sc[6], xd.w*sc[3]+sc[7]};
      float ald[4];
      #pragma unroll
      for (int h=0;h<4;h++)
        ald[h]=xbd[0]*fd[h*4+0]+xbd[1]*fd[h*4+1]+xbd[2]*fd[h*4+2]+xbd[3]*fd[h*4+3];
      int r0=a.rowptr[dst], r1=a.rowptr[dst+1];
      float sum[4]={0,0,0,0};
      float acc[4][4]={{0,0,0,0},{0,0,0,0},{0,0,0,0},{0,0,0,0}};
      for (int i=r0+sub;i<r1;i+=4){
        int s=a.ssrc[i];
        float4 xs=reinterpret_cast<const float4*>(a.x)[s];
        float xb[4]={xs.x*sc[0]+sc[4], xs.y*sc[1]+sc[5], xs.z*sc[2]+sc[6], xs.w*sc[3]+sc[7]};
        #pragma unroll
        for (int h=0;h<4;h++){
          float av=xb[0]*fs[h*4+0]+xb[1]*fs[h*4+1]+xb[2]*fs[h*4+2]+xb[3]*fs[h*4+3];
          float w=__expf(lrelu(av+ald[h]));
          sum[h]+=w;
          acc[h][0]+=w*xb[0]; acc[h][1]+=w*xb[1]; acc[h][2]+=w*xb[2]; acc[h][3]+=w*xb[3];
        }
      }
      #pragma unroll
      for (int m=1;m<4;m<<=1){
        #pragma unroll
        for (int h=0;h<4;h++){
          sum[h]+=__shfl_xor(sum[h],m);
          #pragma unroll
          for (int c=0;c<4;c++) acc[h][c]+=__shfl_xor(acc[h][c],m);
        }
      }
      float G0=acc[0][0],G1=acc[0][1],G2=acc[0][2],G3=acc[0][3],GS=sum[0];
      #pragma unroll
      for (int h=1;h<4;h++){
        if (sub==h){ G0=acc[h][0]; G1=acc[h][1]; G2=acc[h][2]; G3=acc[h][3]; GS=sum[h]; }
      }
      float inv=1.f/(GS+1e-16f);
      G0*=inv; G1*=inv; G2*=inv; G3*=inv;
      float p0=0.f, p1=0.f;
      int ob=sub*32;
      #pragma unroll
      for (int q=0;q<8;q++){
        int o=ob+q*4;
        float4 bb = *reinterpret_cast<const float4*>(a.b_e1+o);
        float4 w0 = *reinterpret_cast<const float4*>(a.w_e1+0*128+o);
        float4 w1 = *reinterpret_cast<const float4*>(a.w_e1+1*128+o);
        float4 w2 = *reinterpret_cast<const float4*>(a.w_e1+2*128+o);
        float4 w3 = *reinterpret_cast<const float4*>(a.w_e1+3*128+o);
        float e0=fmaxf(bb.x+G0*w0.x+G1*w1.x+G2*w2.x+G3*w3.x,0.f);
        float e1=fmaxf(bb.y+G0*w0.y+G1*w1.y+G2*w2.y+G3*w3.y,0.f);
        float e2=fmaxf(bb.z+G0*w0.z+G1*w1.z+G2*w2.z+G3*w3.z,0.f);
        float e3=fmaxf(bb.w+G0*w0.w+G1*w1.w+G2*w2.w+G3*w3.w,0.f);
        float4 wa=*reinterpret_cast<const float4*>(a.w_e3+o*2);
        float4 wb=*reinterpret_cast<const float4*>(a.w_e3+o*2+4);
        p0 += e0*wa.x+e1*wa.z+e2*wb.x+e3*wb.z;
        p1 += e0*wa.y+e1*wa.w+e2*wb.y+e3*wb.w;
      }
      p0+=__shfl_xor(p0,1); p0+=__shfl_xor(p0,2);
      p1+=__shfl_xor(p1,1); p1+=__shfl_xor(p1,2);
      if (sub==0) a.pk2[dst]=make_float2(p0,p1);
    }
  }
  __threadfence(); gg.sync();

  // ================= P6: eagg2 =================
  {
    float as0=a.as_e3[0], as1=a.as_e3[1];
    float ad0=a.ad_e3[0], ad1=a.ad_e3[1];
    float bb0=a.b_e3[0], bb1=a.b_e3[1];
    int sub=t&3;
    for (int dst=b*128+(t>>2); dst<NN; dst+=GRID*128){
      float2 pd=a.pk2[dst];
      float adv=pd.x*ad0+pd.y*ad1;
      int r0=a.rowptr[dst], r1=a.rowptr[dst+1];
      float sum=0.f,a0=0.f,a1=0.f;
      for (int i=r0+sub;i<r1;i+=4){
        int s=a.ssrc[i];
        float2 p=a.pk2[s];
        float w=__expf(lrelu(p.x*as0+p.y*as1+adv));
        sum+=w; a0+=w*p.x; a1+=w*p.y;
      }
      #pragma unroll
      for (int m=1;m<4;m<<=1){
        sum+=__shfl_xor(sum,m); a0+=__shfl_xor(a0,m); a1+=__shfl_xor(a1,m);
      }
      if (sub==0){
        float inv=1.f/(sum+1e-16f);
        a.lat2[dst]=make_float2(a0*inv+bb0, a1*inv+bb1);
      }
    }
  }
  __threadfence(); gg.sync();

  // ================= P7: eagg3 + fused post3 =================
  {
    float f3[8];
    #pragma unroll
    for (int i=0;i<8;i++) f3[i]=a.fold[32+i];
    float f4[8];
    #pragma unroll
    for (int i=0;i<8;i++) f4[i]=a.fold[40+i];
    int sub=t&3;
    for (int dst=b*128+(t>>2); dst<NN; dst+=GRID*128){
      float2 ld=a.lat2[dst];
      float ald[4];
      #pragma unroll
      for (int h=0;h<4;h++) ald[h]=ld.x*f4[h*2+0]+ld.y*f4[h*2+1];
      int r0=a.rowptr[dst], r1=a.rowptr[dst+1];
      float sum[4]={0,0,0,0};
      float acc[4][2]={{0,0},{0,0},{0,0},{0,0}};
      for (int i=r0+sub;i<r1;i+=4){
        int s=a.ssrc[i];
        float2 l=a.lat2[s];
        #pragma unroll
        for (int h=0;h<4;h++){
          float av=l.x*f3[h*2+0]+l.y*f3[h*2+1];
          float w=__expf(lrelu(av+ald[h]));
          sum[h]+=w;
          acc[h][0]+=w*l.x; acc[h][1]+=w*l.y;
        }
      }
      #pragma unroll
      for (int m=1;m<4;m<<=1){
        #pragma unroll
        for (int h=0;h<4;h++){
          sum[h]+=__shfl_xor(sum[h],m);
          acc[h][0]+=__shfl_xor(acc[h][0],m);
          acc[h][1]+=__shfl_xor(acc[h][1],m);
        }
      }
      float G0=acc[0][0],G1=acc[0][1],GS=sum[0];
      #pragma unroll
      for (int h=1;h<4;h++){
        if (sub==h){ G0=acc[h][0]; G1=acc[h][1]; GS=sum[h]; }
      }
      float inv=1.f/(GS+1e-16f);
      G0*=inv; G1*=inv;
      float p0=0.f,p1=0.f,p2=0.f,p3=0.f;
      int ob=sub*32;
      #pragma unroll
      for (int q=0;q<8;q++){
        int o=ob+q*4;
        float4 bb=*reinterpret_cast<const float4*>(a.b_d1+o);
        float4 w0=*reinterpret_cast<const float4*>(a.w_d1+0*128+o);
        float4 w1=*reinterpret_cast<const float4*>(a.w_d1+1*128+o);
        float e0=fmaxf(bb.x+G0*w0.x+G1*w1.x,0.f);
        float e1=fmaxf(bb.y+G0*w0.y+G1*w1.y,0.f);
        float e2=fmaxf(bb.z+G0*w0.z+G1*w1.z,0.f);
        float e3=fmaxf(bb.w+G0*w0.w+G1*w1.w,0.f);
        float4 d0=*reinterpret_cast<const float4*>(a.w_d3+(o+0)*4);
        float4 d1=*reinterpret_cast<const float4*>(a.w_d3+(o+1)*4);
        float4 d2=*reinterpret_cast<const float4*>(a.w_d3+(o+2)*4);
        float4 d3v=*reinterpret_cast<const float4*>(a.w_d3+(o+3)*4);
        p0+=e0*d0.x+e1*d1.x+e2*d2.x+e3*d3v.x;
        p1+=e0*d0.y+e1*d1.y+e2*d2.y+e3*d3v.y;
        p2+=e0*d0.z+e1*d1.z+e2*d2.z+e3*d3v.z;
        p3+=e0*d0.w+e1*d1.w+e2*d2.w+e3*d3v.w;
      }
      #pragma unroll
      for (int m=1;m<4;m<<=1){
        p0+=__shfl_xor(p0,m); p1+=__shfl_xor(p1,m);
        p2+=__shfl_xor(p2,m); p3+=__shfl_xor(p3,m);
      }
      if (sub==0) a.pk4[dst]=make_float4(p0,p1,p2,p3);
    }
  }
  __threadfence(); gg.sync();

  // ================= P8: eagg4 -> output =================
  {
    float as0=a.as_d3[0], as1=a.as_d3[1], as2=a.as_d3[2], as3=a.as_d3[3];
    float ad0=a.ad_d3[0], ad1=a.ad_d3[1], ad2=a.ad_d3[2], ad3=a.ad_d3[3];
    float bb0=a.b_d3[0], bb1=a.b_d3[1], bb2=a.b_d3[2], bb3=a.b_d3[3];
    int sub=t&3;
    for (int dst=b*128+(t>>2); dst<NN; dst+=GRID*128){
      float4 hd=a.pk4[dst];
      float adv=hd.x*ad0+hd.y*ad1+hd.z*ad2+hd.w*ad3;
      int r0=a.rowptr[dst], r1=a.rowptr[dst+1];
      float sum=0.f,a0=0.f,a1=0.f,a2=0.f,a3=0.f;
      for (int i=r0+sub;i<r1;i+=4){
        int s=a.ssrc[i];
        float4 f=a.pk4[s];
        float w=__expf(lrelu(f.x*as0+f.y*as1+f.z*as2+f.w*as3+adv));
        sum+=w; a0+=w*f.x; a1+=w*f.y; a2+=w*f.z; a3+=w*f.w;
      }
      #pragma unroll
      for (int m=1;m<4;m<<=1){
        sum+=__shfl_xor(sum,m);
        a0+=__shfl_xor(a0,m); a1+=__shfl_xor(a1,m);
        a2+=__shfl_xor(a2,m); a3+=__shfl_xor(a3,m);
      }
      if (sub==0){
        float inv=1.f/(sum+1e-16f);
        reinterpret_cast<float4*>(a.out)[dst]=
          make_float4(a0*inv+bb0, a1*inv+bb1, a2*inv+bb2, a3*inv+bb3);
      }
    }
  }
}

// ---------------- launch ----------------
extern "C" void kernel_launch(void* const* d_in, const int* in_sizes, int n_in,
                              void* d_out, int out_size, void* d_ws, size_t ws_size,
                              hipStream_t stream) {
  char* ws = (char*)d_ws;
  size_t off = 0;
  auto alloc = [&](size_t bytes)->void*{
    void* p = ws + off;
    off += (bytes + 255) & ~(size_t)255;
    return p;
  };
  Args a;
  a.x     = (const float*)d_in[0];
  a.ei    = (const int*)  d_in[1];
  a.gamma = (const float*)d_in[2];
  a.beta  = (const float*)d_in[3];
  a.w_e1  = (const float*)d_in[4];
  a.as_e1 = (const float*)d_in[5];
  a.ad_e1 = (const float*)d_in[6];
  a.b_e1  = (const float*)d_in[7];
  a.w_e3  = (const float*)d_in[8];
  a.as_e3 = (const float*)d_in[9];
  a.ad_e3 = (const float*)d_in[10];
  a.b_e3  = (const float*)d_in[11];
  a.w_d1  = (const float*)d_in[12];
  a.as_d1 = (const float*)d_in[13];
  a.ad_d1 = (const float*)d_in[14];
  a.b_d1  = (const float*)d_in[15];
  a.w_d3  = (const float*)d_in[16];
  a.as_d3 = (const float*)d_in[17];
  a.ad_d3 = (const float*)d_in[18];
  a.b_d3  = (const float*)d_in[19];

  a.chunkcnt = (int*)           alloc((size_t)SCN*4);
  a.pofs     = (int*)           alloc((size_t)SCN*4);
  a.bsum     = (int*)           alloc((size_t)GRID*4);
  a.bofs     = (int*)           alloc((size_t)GRID*4);
  a.pedge    = (unsigned int*)  alloc((size_t)ET*4);
  a.rowptr   = (int*)           alloc((size_t)(NN+1)*4);
  a.ssrc     = (unsigned short*)alloc((size_t)ET*2);
  a.part     = (float*)         alloc((size_t)NBP*8*4);
  a.sclsft   = (float*)         alloc(32);
  a.fold     = (float*)         alloc(64*4);
  a.pk2      = (float2*)        alloc((size_t)NN*8);
  a.lat2     = (float2*)        alloc((size_t)NN*8);
  a.pk4      = (float4*)        alloc((size_t)NN*16);
  a.out      = (float*)d_out;

  void* kp[] = { (void*)&a };
  (void)hipLaunchCooperativeKernel((const void*)fused, dim3(GRID), dim3(TPB), kp, 0, stream);
}

// Round 11
// 290.850 us; speedup vs baseline: 2.6362x; 2.6362x over previous
//
#include <hip/hip_runtime.h>

#define NN 50000
#define E0 800000
#define ET 850000          // E0 + NN self loops
#define EPS_BN 1e-5f
#define SLOPE 0.2f
#define NBP 32             // bn partial blocks
#define EPC 2048           // edges per chunk
#define NCH 416            // ceil(ET/EPC)
#define PBITS 8
#define PSZ 256            // dst per partition
#define NP 196             // ceil(NN/256)
#define SCN (NP*NCH)       // 81536 scan elements (partition-major)
#define PER 80             // ceil(SCN/1024)

__device__ __forceinline__ float lrelu(float v){ return v > 0.f ? v : SLOPE*v; }

// ===== K1: per-chunk partition histogram + BN partials; LAST block: scan + BN finalize + fold =====
// sclsft[0..3]=scale, [4..7]=shift
// fold[0:16) ws1[h*4+i]  fold[16:32) wd1[h*4+i]  fold[32:40) ws3[h*2+i]  fold[40:48) wd3[h*2+i]
__global__ __launch_bounds__(1024) void k1_hist_bn_scan(
    const int* __restrict__ ei, const float* __restrict__ x,
    int* __restrict__ chunkcnt, float* __restrict__ part, unsigned* __restrict__ counter,
    const float* __restrict__ gamma, const float* __restrict__ beta,
    const float* __restrict__ w_e1, const float* __restrict__ as_e1, const float* __restrict__ ad_e1,
    const float* __restrict__ w_d1, const float* __restrict__ as_d1, const float* __restrict__ ad_d1,
    int* __restrict__ pofs, float* __restrict__ sclsft, float* __restrict__ fold){
  __shared__ int cc[NP];
  __shared__ float bnlds[16][8];
  __shared__ int sh[1024];
  __shared__ int lastf;
  const int b = blockIdx.x, t = threadIdx.x;

  for (int i=t;i<NP;i+=1024) cc[i]=0;
  __syncthreads();
  int base=b*EPC, end=min(base+EPC,ET);
  for (int e=base+t; e<end; e+=1024){
    int dst = (e<E0) ? ei[E0+e] : (e-E0);
    atomicAdd(&cc[dst>>PBITS],1);
  }
  __syncthreads();
  for (int i=t;i<NP;i+=1024) chunkcnt[b*NP+i]=cc[i];

  if (b < NBP){
    float s[4]={0,0,0,0}, q[4]={0,0,0,0};
    for (int n=b*1024+t; n<NN; n+=NBP*1024){
      float4 v = reinterpret_cast<const float4*>(x)[n];
      s[0]+=v.x; s[1]+=v.y; s[2]+=v.z; s[3]+=v.w;
      q[0]+=v.x*v.x; q[1]+=v.y*v.y; q[2]+=v.z*v.z; q[3]+=v.w*v.w;
    }
    #pragma unroll
    for (int m=1;m<64;m<<=1){
      #pragma unroll
      for (int i=0;i<4;i++){ s[i]+=__shfl_xor(s[i],m); q[i]+=__shfl_xor(q[i],m); }
    }
    int wid=t>>6, lane=t&63;
    if (lane==0){
      #pragma unroll
      for (int i=0;i<4;i++){ bnlds[wid][i]=s[i]; bnlds[wid][4+i]=q[i]; }
    }
    __syncthreads();
    if (t<8){
      float p=0.f;
      #pragma unroll
      for (int w=0;w<16;w++) p += bnlds[w][t];
      part[b*8+t]=p;
    }
  }

  // last-arriving block performs the global scan + BN finalize + fold
  __threadfence();
  if (t==0){
    unsigned old = atomicAdd(counter, 1u);
    lastf = (((old+1u) % (unsigned)NCH) == 0u);   // works for any initial counter value
  }
  __syncthreads();
  if (!lastf) return;
  __threadfence();

  // scan of chunkcnt in partition-major order -> pofs (two-pass, no big register arrays)
  int mysum=0;
  for (int k=0;k<PER;k++){
    int idx=t*PER+k;
    if (idx<SCN){ int p=idx/NCH, ch=idx-p*NCH; mysum += chunkcnt[ch*NP+p]; }
  }
  sh[t]=mysum; __syncthreads();
  int val=mysum;
  for (int off=1;off<1024;off<<=1){
    int tmp=(t>=off)? sh[t-off] : 0; __syncthreads();
    val+=tmp; sh[t]=val; __syncthreads();
  }
  int run=val-mysum;
  for (int k=0;k<PER;k++){
    int idx=t*PER+k;
    if (idx<SCN){
      int p=idx/NCH, ch=idx-p*NCH;
      int v=chunkcnt[ch*NP+p];
      pofs[ch*NP+p]=run;
      run+=v;
    }
  }

  if (t<64){
    int ch=t&7, bslot=t>>3;
    float s=0.f;
    for (int bb=bslot; bb<NBP; bb+=8) s += part[bb*8+ch];
    s += __shfl_xor(s,8); s += __shfl_xor(s,16); s += __shfl_xor(s,32);
    float qv = __shfl(s,(t&3)+4);
    if (t<4){
      float mu  = s*(1.0f/NN);
      float var = qv*(1.0f/NN) - mu*mu;
      float scl = rsqrtf(var + EPS_BN)*gamma[t];
      sclsft[t]   = scl;
      sclsft[4+t] = beta[t] - mu*scl;
    }
  } else if (t<128){
    int u=t-64;
    if (u<32){
      int idx=u&15; int h=idx>>2; int i=idx&3;
      const float* a = (u<16) ? as_e1 : ad_e1;
      float sum=0.f;
      for (int c=0;c<32;c++) sum += w_e1[i*128+h*32+c]*a[h*32+c];
      fold[u]=sum;
    } else if (u<48){
      int idx=u-32; int j=idx&7; int h=j>>1; int i=j&1;
      const float* a = (idx<8) ? as_d1 : ad_d1;
      float sum=0.f;
      for (int c=0;c<32;c++) sum += w_d1[i*128+h*32+c]*a[h*32+c];
      fold[32+idx]=sum;
    }
  }
}

// ===== K2: partition pass (chunk-exclusive runs, packed 4B edges) =====
__global__ __launch_bounds__(256) void partition_pass(const int* __restrict__ ei,
                                                      const int* __restrict__ pofs,
                                                      unsigned* __restrict__ pedge){
  __shared__ int cur[NP];
  const int b=blockIdx.x, t=threadIdx.x;
  for (int i=t;i<NP;i+=256) cur[i]=pofs[b*NP+i];
  __syncthreads();
  int base=b*EPC, end=min(base+EPC,ET);
  for (int e=base+t; e<end; e+=256){
    int src,dst;
    if (e<E0){ src=ei[e]; dst=ei[E0+e]; } else { src=dst=e-E0; }
    int pos=atomicAdd(&cur[dst>>PBITS],1);
    pedge[pos] = ((unsigned)src<<PBITS) | (unsigned)(dst&(PSZ-1));
  }
}

// ===== K3: fine build -> rowptr + ssrc (u16) =====
__global__ __launch_bounds__(1024) void fine_build(const unsigned* __restrict__ pedge,
                                                   const int* __restrict__ pofs,
                                                   int* __restrict__ rowptr,
                                                   unsigned short* __restrict__ ssrc){
  const int p=blockIdx.x, t=threadIdx.x;
  int pstart=pofs[p];                     // pofs[0*NP+p] = partition start
  int pend=(p+1<NP)? pofs[p+1] : ET;
  int dbase=p<<PBITS;
  __shared__ int hist[PSZ];
  __shared__ int cur[PSZ];
  if (t<PSZ) hist[t]=0;
  __syncthreads();
  for (int i=pstart+t;i<pend;i+=1024) atomicAdd(&hist[pedge[i]&(PSZ-1)],1);
  __syncthreads();
  int o=(t<PSZ)? hist[t] : 0;
  __syncthreads();
  int v=o;
  for (int off=1;off<PSZ;off<<=1){
    int tmp=(t>=off && t<PSZ)? hist[t-off] : 0;
    __syncthreads();
    if (t<PSZ){ v+=tmp; hist[t]=v; }
    __syncthreads();
  }
  if (t<PSZ){
    int excl=v-o;
    int d=dbase+t;
    if (d<NN) rowptr[d]=pstart+excl;
    cur[t]=pstart+excl;
  }
  if (p==NP-1 && t==0) rowptr[NN]=ET;
  __syncthreads();
  for (int i=pstart+t;i<pend;i+=1024){
    unsigned e=pedge[i];
    int pos=atomicAdd(&cur[e&(PSZ-1)],1);
    ssrc[pos]=(unsigned short)(e>>PBITS);
  }
}

// ===== eagg1: layer-1 (BN + scores recomputed per edge) + fused post1 =====
__global__ __launch_bounds__(256) void eagg1(
    const float* __restrict__ x, const float* __restrict__ sclsft, const float* __restrict__ fold,
    const int* __restrict__ rowptr, const unsigned short* __restrict__ ssrc,
    const float* __restrict__ w_e1, const float* __restrict__ b_e1, const float* __restrict__ w_e3,
    float2* __restrict__ pk2){
  int dst = blockIdx.x*64 + (threadIdx.x>>2);
  int sub = threadIdx.x & 3;
  if (dst >= NN) return;
  float sc[8];
  #pragma unroll
  for (int i=0;i<8;i++) sc[i] = sclsft[i];
  float fs[16];
  #pragma unroll
  for (int i=0;i<16;i++) fs[i] = fold[i];
  float4 xd = reinterpret_cast<const float4*>(x)[dst];
  float xbd[4] = {xd.x*sc[0]+sc[4], xd.y*sc[1]+sc[5], xd.z*sc[2]+sc[6], xd.w*sc[3]+sc[7]};
  float ald[4];
  #pragma unroll
  for (int h=0;h<4;h++)
    ald[h] = xbd[0]*fold[16+h*4+0] + xbd[1]*fold[16+h*4+1]
           + xbd[2]*fold[16+h*4+2] + xbd[3]*fold[16+h*4+3];
  int r0 = rowptr[dst], r1 = rowptr[dst+1];
  float sum[4] = {0,0,0,0};
  float acc[4][4] = {{0,0,0,0},{0,0,0,0},{0,0,0,0},{0,0,0,0}};
  for (int i = r0 + sub; i < r1; i += 4){
    int s = ssrc[i];
    float4 xs = reinterpret_cast<const float4*>(x)[s];
    float xb[4] = {xs.x*sc[0]+sc[4], xs.y*sc[1]+sc[5], xs.z*sc[2]+sc[6], xs.w*sc[3]+sc[7]};
    #pragma unroll
    for (int h=0;h<4;h++){
      float a = xb[0]*fs[h*4+0] + xb[1]*fs[h*4+1] + xb[2]*fs[h*4+2] + xb[3]*fs[h*4+3];
      float w = __expf(lrelu(a + ald[h]));
      sum[h] += w;
      acc[h][0] += w*xb[0]; acc[h][1] += w*xb[1]; acc[h][2] += w*xb[2]; acc[h][3] += w*xb[3];
    }
  }
  #pragma unroll
  for (int m=1;m<4;m<<=1){
    #pragma unroll
    for (int h=0;h<4;h++){
      sum[h] += __shfl_xor(sum[h],m);
      #pragma unroll
      for (int c=0;c<4;c++) acc[h][c] += __shfl_xor(acc[h][c],m);
    }
  }
  float G0=acc[0][0], G1=acc[0][1], G2=acc[0][2], G3=acc[0][3], GS=sum[0];
  #pragma unroll
  for (int h=1;h<4;h++){
    if (sub==h){ G0=acc[h][0]; G1=acc[h][1]; G2=acc[h][2]; G3=acc[h][3]; GS=sum[h]; }
  }
  float inv = 1.f/(GS+1e-16f);
  G0*=inv; G1*=inv; G2*=inv; G3*=inv;
  float p0 = 0.f, p1 = 0.f;
  int ob = sub*32;
  #pragma unroll
  for (int q=0;q<8;q++){
    int o = ob + q*4;
    float4 b  = *reinterpret_cast<const float4*>(b_e1 + o);
    float4 w0 = *reinterpret_cast<const float4*>(w_e1 + 0*128 + o);
    float4 w1 = *reinterpret_cast<const float4*>(w_e1 + 1*128 + o);
    float4 w2 = *reinterpret_cast<const float4*>(w_e1 + 2*128 + o);
    float4 w3 = *reinterpret_cast<const float4*>(w_e1 + 3*128 + o);
    float e0 = fmaxf(b.x + G0*w0.x + G1*w1.x + G2*w2.x + G3*w3.x, 0.f);
    float e1 = fmaxf(b.y + G0*w0.y + G1*w1.y + G2*w2.y + G3*w3.y, 0.f);
    float e2 = fmaxf(b.z + G0*w0.z + G1*w1.z + G2*w2.z + G3*w3.z, 0.f);
    float e3 = fmaxf(b.w + G0*w0.w + G1*w1.w + G2*w2.w + G3*w3.w, 0.f);
    float4 wa = *reinterpret_cast<const float4*>(w_e3 + o*2);
    float4 wb = *reinterpret_cast<const float4*>(w_e3 + o*2 + 4);
    p0 += e0*wa.x + e1*wa.z + e2*wb.x + e3*wb.z;
    p1 += e0*wa.y + e1*wa.w + e2*wb.y + e3*wb.w;
  }
  p0 += __shfl_xor(p0,1); p0 += __shfl_xor(p0,2);
  p1 += __shfl_xor(p1,1); p1 += __shfl_xor(p1,2);
  if (sub==0) pk2[dst] = make_float2(p0, p1);
}

// ===== eagg2: layer-2 (scores recomputed from pk2) =====
__global__ __launch_bounds__(256) void eagg2(
    const float2* __restrict__ pk2,
    const int* __restrict__ rowptr, const unsigned short* __restrict__ ssrc,
    const float* __restrict__ as_e3, const float* __restrict__ ad_e3, const float* __restrict__ b_e3,
    float2* __restrict__ lat2){
  int dst = blockIdx.x*64 + (threadIdx.x>>2);
  int sub = threadIdx.x & 3;
  if (dst >= NN) return;
  float as0 = as_e3[0], as1 = as_e3[1];
  float2 pd = pk2[dst];
  float adv = pd.x*ad_e3[0] + pd.y*ad_e3[1];
  int r0 = rowptr[dst], r1 = rowptr[dst+1];
  float sum = 0.f, a0 = 0.f, a1 = 0.f;
  for (int i = r0 + sub; i < r1; i += 4){
    int s = ssrc[i];
    float2 p = pk2[s];
    float w = __expf(lrelu(p.x*as0 + p.y*as1 + adv));
    sum += w; a0 += w*p.x; a1 += w*p.y;
  }
  #pragma unroll
  for (int m=1;m<4;m<<=1){
    sum += __shfl_xor(sum,m); a0 += __shfl_xor(a0,m); a1 += __shfl_xor(a1,m);
  }
  if (sub==0){
    float inv = 1.f/(sum+1e-16f);
    lat2[dst] = make_float2(a0*inv + b_e3[0], a1*inv + b_e3[1]);
  }
}

// ===== eagg3: layer-3 (scores recomputed from lat2 via fold) + fused post3 =====
__global__ __launch_bounds__(256) void eagg3(
    const float2* __restrict__ lat2, const float* __restrict__ fold,
    const int* __restrict__ rowptr, const unsigned short* __restrict__ ssrc,
    const float* __restrict__ w_d1, const float* __restrict__ b_d1, const float* __restrict__ w_d3,
    float4* __restrict__ pk4){
  int dst = blockIdx.x*64 + (threadIdx.x>>2);
  int sub = threadIdx.x & 3;
  if (dst >= NN) return;
  float f3[8];
  #pragma unroll
  for (int i=0;i<8;i++) f3[i] = fold[32+i];
  float2 ld = lat2[dst];
  float ald[4];
  #pragma unroll
  for (int h=0;h<4;h++) ald[h] = ld.x*fold[40+h*2+0] + ld.y*fold[40+h*2+1];
  int r0 = rowptr[dst], r1 = rowptr[dst+1];
  float sum[4] = {0,0,0,0};
  float acc[4][2] = {{0,0},{0,0},{0,0},{0,0}};
  for (int i = r0 + sub; i < r1; i += 4){
    int s = ssrc[i];
    float2 l = lat2[s];
    #pragma unroll
    for (int h=0;h<4;h++){
      float a = l.x*f3[h*2+0] + l.y*f3[h*2+1];
      float w = __expf(lrelu(a + ald[h]));
      sum[h] += w;
      acc[h][0] += w*l.x; acc[h][1] += w*l.y;
    }
  }
  #pragma unroll
  for (int m=1;m<4;m<<=1){
    #pragma unroll
    for (int h=0;h<4;h++){
      sum[h] += __shfl_xor(sum[h],m);
      acc[h][0] += __shfl_xor(acc[h][0],m);
      acc[h][1] += __shfl_xor(acc[h][1],m);
    }
  }
  float G0=acc[0][0], G1=acc[0][1], GS=sum[0];
  #pragma unroll
  for (int h=1;h<4;h++){
    if (sub==h){ G0=acc[h][0]; G1=acc[h][1]; GS=sum[h]; }
  }
  float inv = 1.f/(GS+1e-16f);
  G0*=inv; G1*=inv;
  float p0=0.f,p1=0.f,p2=0.f,p3=0.f;
  int ob = sub*32;
  #pragma unroll
  for (int q=0;q<8;q++){
    int o = ob + q*4;
    float4 b  = *reinterpret_cast<const float4*>(b_d1 + o);
    float4 w0 = *reinterpret_cast<const float4*>(w_d1 + 0*128 + o);
    float4 w1 = *reinterpret_cast<const float4*>(w_d1 + 1*128 + o);
    float e0 = fmaxf(b.x + G0*w0.x + G1*w1.x, 0.f);
    float e1 = fmaxf(b.y + G0*w0.y + G1*w1.y, 0.f);
    float e2 = fmaxf(b.z + G0*w0.z + G1*w1.z, 0.f);
    float e3 = fmaxf(b.w + G0*w0.w + G1*w1.w, 0.f);
    float4 d0 = *reinterpret_cast<const float4*>(w_d3 + (o+0)*4);
    float4 d1 = *reinterpret_cast<const float4*>(w_d3 + (o+1)*4);
    float4 d2 = *reinterpret_cast<const float4*>(w_d3 + (o+2)*4);
    float4 d3v= *reinterpret_cast<const float4*>(w_d3 + (o+3)*4);
    p0 += e0*d0.x + e1*d1.x + e2*d2.x + e3*d3v.x;
    p1 += e0*d0.y + e1*d1.y + e2*d2.y + e3*d3v.y;
    p2 += e0*d0.z + e1*d1.z + e2*d2.z + e3*d3v.z;
    p3 += e0*d0.w + e1*d1.w + e2*d2.w + e3*d3v.w;
  }
  #pragma unroll
  for (int m=1;m<4;m<<=1){
    p0 += __shfl_xor(p0,m); p1 += __shfl_xor(p1,m);
    p2 += __shfl_xor(p2,m); p3 += __shfl_xor(p3,m);
  }
  if (sub==0) pk4[dst] = make_float4(p0,p1,p2,p3);
}

// ===== eagg4: layer-4 (scores recomputed from pk4) -> output =====
__global__ __launch_bounds__(256) void eagg4(
    const float4* __restrict__ pk4,
    const int* __restrict__ rowptr, const unsigned short* __restrict__ ssrc,
    const float* __restrict__ as_d3, const float* __restrict__ ad_d3, const float* __restrict__ b_d3,
    float* __restrict__ out){
  int dst = blockIdx.x*64 + (threadIdx.x>>2);
  int sub = threadIdx.x & 3;
  if (dst >= NN) return;
  float as0=as_d3[0], as1=as_d3[1], as2=as_d3[2], as3=as_d3[3];
  float4 hd = pk4[dst];
  float adv = hd.x*ad_d3[0] + hd.y*ad_d3[1] + hd.z*ad_d3[2] + hd.w*ad_d3[3];
  int r0 = rowptr[dst], r1 = rowptr[dst+1];
  float sum = 0.f, a0=0.f, a1=0.f, a2=0.f, a3=0.f;
  for (int i = r0 + sub; i < r1; i += 4){
    int s = ssrc[i];
    float4 f = pk4[s];
    float w = __expf(lrelu(f.x*as0 + f.y*as1 + f.z*as2 + f.w*as3 + adv));
    sum += w; a0 += w*f.x; a1 += w*f.y; a2 += w*f.z; a3 += w*f.w;
  }
  #pragma unroll
  for (int m=1;m<4;m<<=1){
    sum += __shfl_xor(sum,m);
    a0 += __shfl_xor(a0,m); a1 += __shfl_xor(a1,m);
    a2 += __shfl_xor(a2,m); a3 += __shfl_xor(a3,m);
  }
  if (sub==0){
    float inv = 1.f/(sum+1e-16f);
    reinterpret_cast<float4*>(out)[dst] =
      make_float4(a0*inv+b_d3[0], a1*inv+b_d3[1], a2*inv+b_d3[2], a3*inv+b_d3[3]);
  }
}

// ---------------- launch ----------------
extern "C" void kernel_launch(void* const* d_in, const int* in_sizes, int n_in,
                              void* d_out, int out_size, void* d_ws, size_t ws_size,
                              hipStream_t stream) {
  const float* x     = (const float*)d_in[0];
  const int*   ei    = (const int*)  d_in[1];
  const float* gamma = (const float*)d_in[2];
  const float* beta  = (const float*)d_in[3];
  const float* w_e1  = (const float*)d_in[4];
  const float* as_e1 = (const float*)d_in[5];
  const float* ad_e1 = (const float*)d_in[6];
  const float* b_e1  = (const float*)d_in[7];
  const float* w_e3  = (const float*)d_in[8];
  const float* as_e3 = (const float*)d_in[9];
  const float* ad_e3 = (const float*)d_in[10];
  const float* b_e3  = (const float*)d_in[11];
  const float* w_d1  = (const float*)d_in[12];
  const float* as_d1 = (const float*)d_in[13];
  const float* ad_d1 = (const float*)d_in[14];
  const float* b_d1  = (const float*)d_in[15];
  const float* w_d3  = (const float*)d_in[16];
  const float* as_d3 = (const float*)d_in[17];
  const float* ad_d3 = (const float*)d_in[18];
  const float* b_d3  = (const float*)d_in[19];

  char* ws = (char*)d_ws;
  size_t off = 0;
  auto alloc = [&](size_t bytes)->void*{
    void* p = ws + off;
    off += (bytes + 255) & ~(size_t)255;
    return p;
  };
  int*      chunkcnt = (int*)           alloc((size_t)SCN*4);
  int*      pofs     = (int*)           alloc((size_t)SCN*4);
  unsigned* pedge    = (unsigned*)      alloc((size_t)ET*4);
  int*      rowptr   = (int*)           alloc((size_t)(NN+1)*4);
  unsigned short* ssrc = (unsigned short*)alloc((size_t)ET*2);
  float*    part     = (float*)         alloc((size_t)NBP*8*4);
  float*    sclsft   = (float*)         alloc(32);
  float*    fold     = (float*)         alloc(64*4);
  unsigned* counter  = (unsigned*)      alloc(4);
  float2*   pk2      = (float2*)        alloc((size_t)NN*8);
  float2*   lat2     = (float2*)        alloc((size_t)NN*8);
  float4*   pk4      = (float4*)        alloc((size_t)NN*16);

  // CSR build (3 kernels): hist+BN+(last-block scan/finalize/fold) -> partition -> fine
  k1_hist_bn_scan<<<NCH, 1024, 0, stream>>>(ei, x, chunkcnt, part, counter,
                                            gamma, beta, w_e1, as_e1, ad_e1,
                                            w_d1, as_d1, ad_d1, pofs, sclsft, fold);
  partition_pass<<<NCH, 256, 0, stream>>>(ei, pofs, pedge);
  fine_build<<<NP, 1024, 0, stream>>>(pedge, pofs, rowptr, ssrc);

  const int NAGG = (NN + 63)/64;   // 64 dst per 256-thread block (4 lanes/dst)

  eagg1<<<NAGG, 256, 0, stream>>>(x, sclsft, fold, rowptr, ssrc, w_e1, b_e1, w_e3, pk2);
  eagg2<<<NAGG, 256, 0, stream>>>(pk2, rowptr, ssrc, as_e3, ad_e3, b_e3, lat2);
  eagg3<<<NAGG, 256, 0, stream>>>(lat2, fold, rowptr, ssrc, w_d1, b_d1, w_d3, pk4);
  eagg4<<<NAGG, 256, 0, stream>>>(pk4, rowptr, ssrc, as_d3, ad_d3, b_d3, (float*)d_out);
}

// Round 12
// 122.337 us; speedup vs baseline: 6.2675x; 2.3775x over previous
//
#include <hip/hip_runtime.h>

#define NN 50000
#define E0 800000
#define ET 850000          // E0 + NN self loops
#define EPS_BN 1e-5f
#define SLOPE 0.2f
#define NBP 32             // bn partial blocks
#define EPC 8192           // edges per chunk
#define NCH 104            // ceil(ET/EPC)
#define PBITS 8
#define PSZ 256            // dst per partition
#define NP 196             // ceil(NN/256)
#define SCN (NP*NCH)       // 20384 scan elements, partition-major: idx = p*NCH+ch
#define PER 20             // ceil(SCN/1024)

__device__ __forceinline__ float lrelu(float v){ return v > 0.f ? v : SLOPE*v; }

// ===== K1: per-chunk partition histogram (partition-major store) + BN partials =====
__global__ __launch_bounds__(1024) void chunk_hist_bn(const int* __restrict__ ei, int* __restrict__ chunkcnt,
                                                      const float* __restrict__ x, float* __restrict__ part){
  __shared__ int cc[NP];
  __shared__ float bnlds[16][8];
  const int b = blockIdx.x, t = threadIdx.x;
  for (int i=t;i<NP;i+=1024) cc[i]=0;
  __syncthreads();
  int base=b*EPC, end=min(base+EPC,ET);
  for (int e=base+t; e<end; e+=1024){
    int dst = (e<E0) ? ei[E0+e] : (e-E0);
    atomicAdd(&cc[dst>>PBITS],1);
  }
  __syncthreads();
  for (int i=t;i<NP;i+=1024) chunkcnt[i*NCH + b]=cc[i];   // partition-major

  if (b < NBP){
    float s[4]={0,0,0,0}, q[4]={0,0,0,0};
    for (int n=b*1024+t; n<NN; n+=NBP*1024){
      float4 v = reinterpret_cast<const float4*>(x)[n];
      s[0]+=v.x; s[1]+=v.y; s[2]+=v.z; s[3]+=v.w;
      q[0]+=v.x*v.x; q[1]+=v.y*v.y; q[2]+=v.z*v.z; q[3]+=v.w*v.w;
    }
    #pragma unroll
    for (int m=1;m<64;m<<=1){
      #pragma unroll
      for (int i=0;i<4;i++){ s[i]+=__shfl_xor(s[i],m); q[i]+=__shfl_xor(q[i],m); }
    }
    int wid=t>>6, lane=t&63;
    if (lane==0){
      #pragma unroll
      for (int i=0;i<4;i++){ bnlds[wid][i]=s[i]; bnlds[wid][4+i]=q[i]; }
    }
    __syncthreads();
    if (t<8){
      float p=0.f;
      #pragma unroll
      for (int w=0;w<16;w++) p += bnlds[w][t];
      part[b*8+t]=p;
    }
  }
}

// ===== K2: scan (coalesced partition-major read) + BN finalize + weight fold =====
// pofs[ch*NP+p] (chunk-major) = offset of (chunk ch, partition p) run in pedge.
// sclsft[0..3]=scale, [4..7]=shift
// fold[0:16) ws1[h*4+i]  fold[16:32) wd1[h*4+i]  fold[32:40) ws3[h*2+i]  fold[40:48) wd3[h*2+i]
__global__ __launch_bounds__(1024) void scan_fold(
    const int* __restrict__ chunkcnt, int* __restrict__ pofs,
    const float* __restrict__ part, const float* __restrict__ gamma, const float* __restrict__ beta,
    const float* __restrict__ w_e1, const float* __restrict__ as_e1, const float* __restrict__ ad_e1,
    const float* __restrict__ w_d1, const float* __restrict__ as_d1, const float* __restrict__ ad_d1,
    float* __restrict__ sclsft, float* __restrict__ fold){
  __shared__ int wsum[1024];
  int t = threadIdx.x;
  int vals[PER];
  int mysum = 0;
  #pragma unroll
  for (int k=0;k<PER;k++){
    int idx = t*PER + k;
    int v = (idx < SCN) ? chunkcnt[idx] : 0;   // coalesced-ish: consecutive runs
    vals[k] = v; mysum += v;
  }
  wsum[t] = mysum; __syncthreads();
  int val = mysum;
  for (int off=1; off<1024; off<<=1){
    int tmp = (t>=off) ? wsum[t-off] : 0;
    __syncthreads();
    val += tmp; wsum[t] = val; __syncthreads();
  }
  int run = val - mysum;   // exclusive prefix
  #pragma unroll
  for (int k=0;k<PER;k++){
    int idx = t*PER + k;
    if (idx < SCN){
      int p = idx/NCH, ch = idx - p*NCH;
      pofs[ch*NP + p] = run;
    }
    run += vals[k];
  }

  if (t < 64){
    int ch = t&7, bslot = t>>3;
    float s = 0.f;
    for (int b=bslot; b<NBP; b+=8) s += part[b*8 + ch];
    s += __shfl_xor(s,8); s += __shfl_xor(s,16); s += __shfl_xor(s,32);
    float qv = __shfl(s, (t&3)+4);
    if (t < 4){
      float mu  = s*(1.0f/NN);
      float var = qv*(1.0f/NN) - mu*mu;
      float scl = rsqrtf(var + EPS_BN)*gamma[t];
      sclsft[t]   = scl;
      sclsft[4+t] = beta[t] - mu*scl;
    }
  } else if (t < 128){
    int u = t - 64;
    if (u < 32){
      int idx = u & 15; int h = idx>>2; int i = idx&3;
      const float* a = (u<16) ? as_e1 : ad_e1;
      float sum = 0.f;
      for (int c=0;c<32;c++) sum += w_e1[i*128 + h*32 + c] * a[h*32 + c];
      fold[u] = sum;
    } else if (u < 48){
      int idx = u - 32; int j = idx & 7; int h = j>>1; int i = j&1;
      const float* a = (idx<8) ? as_d1 : ad_d1;
      float sum = 0.f;
      for (int c=0;c<32;c++) sum += w_d1[i*128 + h*32 + c] * a[h*32 + c];
      fold[32 + idx] = sum;
    }
  }
}

// ===== K3: partition pass (chunk-exclusive runs, packed 4B edges) =====
__global__ __launch_bounds__(1024) void partition_pass(const int* __restrict__ ei,
                                                       const int* __restrict__ pofs,
                                                       unsigned* __restrict__ pedge){
  __shared__ int cur[NP];
  const int b=blockIdx.x, t=threadIdx.x;
  for (int i=t;i<NP;i+=1024) cur[i]=pofs[b*NP+i];
  __syncthreads();
  int base=b*EPC, end=min(base+EPC,ET);
  for (int e=base+t; e<end; e+=1024){
    int src,dst;
    if (e<E0){ src=ei[e]; dst=ei[E0+e]; } else { src=dst=e-E0; }
    int pos=atomicAdd(&cur[dst>>PBITS],1);
    pedge[pos] = ((unsigned)src<<PBITS) | (unsigned)(dst&(PSZ-1));
  }
}

// ===== K4: fine build (rowptr + u16 ssrc) FUSED with eagg1 (layer-1 + post1) =====
// Block = partition (1024 threads = 4 lanes x 256 dst). After the in-block scatter,
// row bounds are in LDS and ssrc window is L2-hot -> immediate aggregation.
__global__ __launch_bounds__(1024) void fine_eagg1(
    const unsigned* __restrict__ pedge, const int* __restrict__ pofs,
    int* __restrict__ rowptr, unsigned short* __restrict__ ssrc,
    const float* __restrict__ x, const float* __restrict__ sclsft, const float* __restrict__ fold,
    const float* __restrict__ w_e1, const float* __restrict__ b_e1, const float* __restrict__ w_e3,
    float2* __restrict__ pk2){
  const int p=blockIdx.x, t=threadIdx.x;
  int pstart=pofs[p];                     // chunk-major: pofs[0*NP+p]
  int pend=(p+1<NP)? pofs[p+1] : ET;
  int dbase=p<<PBITS;
  __shared__ int hist[PSZ];
  __shared__ int rstart[PSZ];
  __shared__ int cur[PSZ];
  if (t<PSZ) hist[t]=0;
  __syncthreads();
  for (int i=pstart+t;i<pend;i+=1024) atomicAdd(&hist[pedge[i]&(PSZ-1)],1);
  __syncthreads();
  int o=(t<PSZ)? hist[t] : 0;
  __syncthreads();
  int v=o;
  for (int off=1;off<PSZ;off<<=1){
    int tmp=(t>=off && t<PSZ)? hist[t-off] : 0;
    __syncthreads();
    if (t<PSZ){ v+=tmp; hist[t]=v; }
    __syncthreads();
  }
  if (t<PSZ){
    int excl=v-o;
    int d=dbase+t;
    if (d<NN) rowptr[d]=pstart+excl;
    rstart[t]=pstart+excl;
    cur[t]=pstart+excl;
  }
  if (p==NP-1 && t==0) rowptr[NN]=ET;
  __syncthreads();
  for (int i=pstart+t;i<pend;i+=1024){
    unsigned e=pedge[i];
    int pos=atomicAdd(&cur[(int)(e&(PSZ-1))],1);
    ssrc[pos]=(unsigned short)(e>>PBITS);
  }
  __threadfence_block();   // make same-block global ssrc writes visible
  __syncthreads();

  // ---- eagg1 phase: dst = dbase + (t>>2), 4 lanes per dst ----
  int ldst = t>>2;
  int sub = t&3;
  int dst = dbase + ldst;
  if (dst >= NN) return;
  float sc[8];
  #pragma unroll
  for (int i=0;i<8;i++) sc[i] = sclsft[i];
  float fs[16];
  #pragma unroll
  for (int i=0;i<16;i++) fs[i] = fold[i];
  float4 xd = reinterpret_cast<const float4*>(x)[dst];
  float xbd[4] = {xd.x*sc[0]+sc[4], xd.y*sc[1]+sc[5], xd.z*sc[2]+sc[6], xd.w*sc[3]+sc[7]};
  float ald[4];
  #pragma unroll
  for (int h=0;h<4;h++)
    ald[h] = xbd[0]*fold[16+h*4+0] + xbd[1]*fold[16+h*4+1]
           + xbd[2]*fold[16+h*4+2] + xbd[3]*fold[16+h*4+3];
  int r0 = rstart[ldst], r1 = cur[ldst];
  float sum[4] = {0,0,0,0};
  float acc[4][4] = {{0,0,0,0},{0,0,0,0},{0,0,0,0},{0,0,0,0}};
  for (int i = r0 + sub; i < r1; i += 4){
    int s = ssrc[i];
    float4 xs = reinterpret_cast<const float4*>(x)[s];
    float xb[4] = {xs.x*sc[0]+sc[4], xs.y*sc[1]+sc[5], xs.z*sc[2]+sc[6], xs.w*sc[3]+sc[7]};
    #pragma unroll
    for (int h=0;h<4;h++){
      float a = xb[0]*fs[h*4+0] + xb[1]*fs[h*4+1] + xb[2]*fs[h*4+2] + xb[3]*fs[h*4+3];
      float w = __expf(lrelu(a + ald[h]));
      sum[h] += w;
      acc[h][0] += w*xb[0]; acc[h][1] += w*xb[1]; acc[h][2] += w*xb[2]; acc[h][3] += w*xb[3];
    }
  }
  #pragma unroll
  for (int m=1;m<4;m<<=1){
    #pragma unroll
    for (int h=0;h<4;h++){
      sum[h] += __shfl_xor(sum[h],m);
      #pragma unroll
      for (int c=0;c<4;c++) acc[h][c] += __shfl_xor(acc[h][c],m);
    }
  }
  float G0=acc[0][0], G1=acc[0][1], G2=acc[0][2], G3=acc[0][3], GS=sum[0];
  #pragma unroll
  for (int h=1;h<4;h++){
    if (sub==h){ G0=acc[h][0]; G1=acc[h][1]; G2=acc[h][2]; G3=acc[h][3]; GS=sum[h]; }
  }
  float inv = 1.f/(GS+1e-16f);
  G0*=inv; G1*=inv; G2*=inv; G3*=inv;
  float p0 = 0.f, p1 = 0.f;
  int ob = sub*32;
  #pragma unroll
  for (int q=0;q<8;q++){
    int o2 = ob + q*4;
    float4 b  = *reinterpret_cast<const float4*>(b_e1 + o2);
    float4 w0 = *reinterpret_cast<const float4*>(w_e1 + 0*128 + o2);
    float4 w1 = *reinterpret_cast<const float4*>(w_e1 + 1*128 + o2);
    float4 w2 = *reinterpret_cast<const float4*>(w_e1 + 2*128 + o2);
    float4 w3 = *reinterpret_cast<const float4*>(w_e1 + 3*128 + o2);
    float e0 = fmaxf(b.x + G0*w0.x + G1*w1.x + G2*w2.x + G3*w3.x, 0.f);
    float e1 = fmaxf(b.y + G0*w0.y + G1*w1.y + G2*w2.y + G3*w3.y, 0.f);
    float e2 = fmaxf(b.z + G0*w0.z + G1*w1.z + G2*w2.z + G3*w3.z, 0.f);
    float e3 = fmaxf(b.w + G0*w0.w + G1*w1.w + G2*w2.w + G3*w3.w, 0.f);
    float4 wa = *reinterpret_cast<const float4*>(w_e3 + o2*2);
    float4 wb = *reinterpret_cast<const float4*>(w_e3 + o2*2 + 4);
    p0 += e0*wa.x + e1*wa.z + e2*wb.x + e3*wb.z;
    p1 += e0*wa.y + e1*wa.w + e2*wb.y + e3*wb.w;
  }
  p0 += __shfl_xor(p0,1); p0 += __shfl_xor(p0,2);
  p1 += __shfl_xor(p1,1); p1 += __shfl_xor(p1,2);
  if (sub==0) pk2[dst] = make_float2(p0, p1);
}

// ===== eagg2: layer-2 (scores recomputed from pk2) =====
__global__ __launch_bounds__(256) void eagg2(
    const float2* __restrict__ pk2,
    const int* __restrict__ rowptr, const unsigned short* __restrict__ ssrc,
    const float* __restrict__ as_e3, const float* __restrict__ ad_e3, const float* __restrict__ b_e3,
    float2* __restrict__ lat2){
  int dst = blockIdx.x*64 + (threadIdx.x>>2);
  int sub = threadIdx.x & 3;
  if (dst >= NN) return;
  float as0 = as_e3[0], as1 = as_e3[1];
  float2 pd = pk2[dst];
  float adv = pd.x*ad_e3[0] + pd.y*ad_e3[1];
  int r0 = rowptr[dst], r1 = rowptr[dst+1];
  float sum = 0.f, a0 = 0.f, a1 = 0.f;
  for (int i = r0 + sub; i < r1; i += 4){
    int s = ssrc[i];
    float2 p = pk2[s];
    float w = __expf(lrelu(p.x*as0 + p.y*as1 + adv));
    sum += w; a0 += w*p.x; a1 += w*p.y;
  }
  #pragma unroll
  for (int m=1;m<4;m<<=1){
    sum += __shfl_xor(sum,m); a0 += __shfl_xor(a0,m); a1 += __shfl_xor(a1,m);
  }
  if (sub==0){
    float inv = 1.f/(sum+1e-16f);
    lat2[dst] = make_float2(a0*inv + b_e3[0], a1*inv + b_e3[1]);
  }
}

// ===== eagg3: layer-3 (scores recomputed from lat2 via fold) + fused post3 =====
__global__ __launch_bounds__(256) void eagg3(
    const float2* __restrict__ lat2, const float* __restrict__ fold,
    const int* __restrict__ rowptr, const unsigned short* __restrict__ ssrc,
    const float* __restrict__ w_d1, const float* __restrict__ b_d1, const float* __restrict__ w_d3,
    float4* __restrict__ pk4){
  int dst = blockIdx.x*64 + (threadIdx.x>>2);
  int sub = threadIdx.x & 3;
  if (dst >= NN) return;
  float f3[8];
  #pragma unroll
  for (int i=0;i<8;i++) f3[i] = fold[32+i];
  float2 ld = lat2[dst];
  float ald[4];
  #pragma unroll
  for (int h=0;h<4;h++) ald[h] = ld.x*fold[40+h*2+0] + ld.y*fold[40+h*2+1];
  int r0 = rowptr[dst], r1 = rowptr[dst+1];
  float sum[4] = {0,0,0,0};
  float acc[4][2] = {{0,0},{0,0},{0,0},{0,0}};
  for (int i = r0 + sub; i < r1; i += 4){
    int s = ssrc[i];
    float2 l = lat2[s];
    #pragma unroll
    for (int h=0;h<4;h++){
      float a = l.x*f3[h*2+0] + l.y*f3[h*2+1];
      float w = __expf(lrelu(a + ald[h]));
      sum[h] += w;
      acc[h][0] += w*l.x; acc[h][1] += w*l.y;
    }
  }
  #pragma unroll
  for (int m=1;m<4;m<<=1){
    #pragma unroll
    for (int h=0;h<4;h++){
      sum[h] += __shfl_xor(sum[h],m);
      acc[h][0] += __shfl_xor(acc[h][0],m);
      acc[h][1] += __shfl_xor(acc[h][1],m);
    }
  }
  float G0=acc[0][0], G1=acc[0][1], GS=sum[0];
  #pragma unroll
  for (int h=1;h<4;h++){
    if (sub==h){ G0=acc[h][0]; G1=acc[h][1]; GS=sum[h]; }
  }
  float inv = 1.f/(GS+1e-16f);
  G0*=inv; G1*=inv;
  float p0=0.f,p1=0.f,p2=0.f,p3=0.f;
  int ob = sub*32;
  #pragma unroll
  for (int q=0;q<8;q++){
    int o = ob + q*4;
    float4 b  = *reinterpret_cast<const float4*>(b_d1 + o);
    float4 w0 = *reinterpret_cast<const float4*>(w_d1 + 0*128 + o);
    float4 w1 = *reinterpret_cast<const float4*>(w_d1 + 1*128 + o);
    float e0 = fmaxf(b.x + G0*w0.x + G1*w1.x, 0.f);
    float e1 = fmaxf(b.y + G0*w0.y + G1*w1.y, 0.f);
    float e2 = fmaxf(b.z + G0*w0.z + G1*w1.z, 0.f);
    float e3 = fmaxf(b.w + G0*w0.w + G1*w1.w, 0.f);
    float4 d0 = *reinterpret_cast<const float4*>(w_d3 + (o+0)*4);
    float4 d1 = *reinterpret_cast<const float4*>(w_d3 + (o+1)*4);
    float4 d2 = *reinterpret_cast<const float4*>(w_d3 + (o+2)*4);
    float4 d3v= *reinterpret_cast<const float4*>(w_d3 + (o+3)*4);
    p0 += e0*d0.x + e1*d1.x + e2*d2.x + e3*d3v.x;
    p1 += e0*d0.y + e1*d1.y + e2*d2.y + e3*d3v.y;
    p2 += e0*d0.z + e1*d1.z + e2*d2.z + e3*d3v.z;
    p3 += e0*d0.w + e1*d1.w + e2*d2.w + e3*d3v.w;
  }
  #pragma unroll
  for (int m=1;m<4;m<<=1){
    p0 += __shfl_xor(p0,m); p1 += __shfl_xor(p1,m);
    p2 += __shfl_xor(p2,m); p3 += __shfl_xor(p3,m);
  }
  if (sub==0) pk4[dst] = make_float4(p0,p1,p2,p3);
}

// ===== eagg4: layer-4 (scores recomputed from pk4) -> output =====
__global__ __launch_bounds__(256) void eagg4(
    const float4* __restrict__ pk4,
    const int* __restrict__ rowptr, const unsigned short* __restrict__ ssrc,
    const float* __restrict__ as_d3, const float* __restrict__ ad_d3, const float* __restrict__ b_d3,
    float* __restrict__ out){
  int dst = blockIdx.x*64 + (threadIdx.x>>2);
  int sub = threadIdx.x & 3;
  if (dst >= NN) return;
  float as0=as_d3[0], as1=as_d3[1], as2=as_d3[2], as3=as_d3[3];
  float4 hd = pk4[dst];
  float adv = hd.x*ad_d3[0] + hd.y*ad_d3[1] + hd.z*ad_d3[2] + hd.w*ad_d3[3];
  int r0 = rowptr[dst], r1 = rowptr[dst+1];
  float sum = 0.f, a0=0.f, a1=0.f, a2=0.f, a3=0.f;
  for (int i = r0 + sub; i < r1; i += 4){
    int s = ssrc[i];
    float4 f = pk4[s];
    float w = __expf(lrelu(f.x*as0 + f.y*as1 + f.z*as2 + f.w*as3 + adv));
    sum += w; a0 += w*f.x; a1 += w*f.y; a2 += w*f.z; a3 += w*f.w;
  }
  #pragma unroll
  for (int m=1;m<4;m<<=1){
    sum += __shfl_xor(sum,m);
    a0 += __shfl_xor(a0,m); a1 += __shfl_xor(a1,m);
    a2 += __shfl_xor(a2,m); a3 += __shfl_xor(a3,m);
  }
  if (sub==0){
    float inv = 1.f/(sum+1e-16f);
    reinterpret_cast<float4*>(out)[dst] =
      make_float4(a0*inv+b_d3[0], a1*inv+b_d3[1], a2*inv+b_d3[2], a3*inv+b_d3[3]);
  }
}

// ---------------- launch ----------------
extern "C" void kernel_launch(void* const* d_in, const int* in_sizes, int n_in,
                              void* d_out, int out_size, void* d_ws, size_t ws_size,
                              hipStream_t stream) {
  const float* x     = (const float*)d_in[0];
  const int*   ei    = (const int*)  d_in[1];
  const float* gamma = (const float*)d_in[2];
  const float* beta  = (const float*)d_in[3];
  const float* w_e1  = (const float*)d_in[4];
  const float* as_e1 = (const float*)d_in[5];
  const float* ad_e1 = (const float*)d_in[6];
  const float* b_e1  = (const float*)d_in[7];
  const float* w_e3  = (const float*)d_in[8];
  const float* as_e3 = (const float*)d_in[9];
  const float* ad_e3 = (const float*)d_in[10];
  const float* b_e3  = (const float*)d_in[11];
  const float* w_d1  = (const float*)d_in[12];
  const float* as_d1 = (const float*)d_in[13];
  const float* ad_d1 = (const float*)d_in[14];
  const float* b_d1  = (const float*)d_in[15];
  const float* w_d3  = (const float*)d_in[16];
  const float* as_d3 = (const float*)d_in[17];
  const float* ad_d3 = (const float*)d_in[18];
  const float* b_d3  = (const float*)d_in[19];

  char* ws = (char*)d_ws;
  size_t off = 0;
  auto alloc = [&](size_t bytes)->void*{
    void* p = ws + off;
    off += (bytes + 255) & ~(size_t)255;
    return p;
  };
  int*      chunkcnt = (int*)            alloc((size_t)SCN*4);
  int*      pofs     = (int*)            alloc((size_t)SCN*4);
  unsigned* pedge    = (unsigned*)       alloc((size_t)ET*4);
  int*      rowptr   = (int*)            alloc((size_t)(NN+1)*4);
  unsigned short* ssrc = (unsigned short*)alloc((size_t)ET*2);
  float*    part     = (float*)          alloc((size_t)NBP*8*4);
  float*    sclsft   = (float*)          alloc(32);
  float*    fold     = (float*)          alloc(64*4);
  float2*   pk2      = (float2*)         alloc((size_t)NN*8);
  float2*   lat2     = (float2*)         alloc((size_t)NN*8);
  float4*   pk4      = (float4*)         alloc((size_t)NN*16);

  chunk_hist_bn<<<NCH, 1024, 0, stream>>>(ei, chunkcnt, x, part);
  scan_fold<<<1, 1024, 0, stream>>>(chunkcnt, pofs, part, gamma, beta,
                                    w_e1, as_e1, ad_e1, w_d1, as_d1, ad_d1, sclsft, fold);
  partition_pass<<<NCH, 1024, 0, stream>>>(ei, pofs, pedge);
  fine_eagg1<<<NP, 1024, 0, stream>>>(pedge, pofs, rowptr, ssrc,
                                      x, sclsft, fold, w_e1, b_e1, w_e3, pk2);

  const int NAGG = (NN + 63)/64;   // 64 dst per 256-thread block (4 lanes/dst)
  eagg2<<<NAGG, 256, 0, stream>>>(pk2, rowptr, ssrc, as_e3, ad_e3, b_e3, lat2);
  eagg3<<<NAGG, 256, 0, stream>>>(lat2, fold, rowptr, ssrc, w_d1, b_d1, w_d3, pk4);
  eagg4<<<NAGG, 256, 0, stream>>>(pk4, rowptr, ssrc, as_d3, ad_d3, b_d3, (float*)d_out);
}

// Round 13
// 107.914 us; speedup vs baseline: 7.1052x; 1.1337x over previous
//
#include <hip/hip_runtime.h>

#define NN 50000
#define E0 800000
#define ET 850000          // E0 + NN self loops
#define EPS_BN 1e-5f
#define SLOPE 0.2f
#define NBP 32             // bn partial blocks
#define EPC 4096           // edges per chunk
#define NCH 208            // ceil(ET/EPC)
#define PBITS 7
#define PSZ 128            // dst per partition
#define NP 391             // ceil(NN/128)
#define CAP 3072           // window capacity per partition (mean 2176, +20 sigma)

__device__ __forceinline__ float lrelu(float v){ return v > 0.f ? v : SLOPE*v; }

// ===== K1: single-pass edge stage + atomic window allocation + BN partials =====
// pedge[p*CAP + ...] = (src<<16)|dst for edges with dst in partition p.
__global__ __launch_bounds__(512) void k1_stage(const int* __restrict__ ei, const float* __restrict__ x,
                                                unsigned* __restrict__ pedge, int* __restrict__ gcur,
                                                float* __restrict__ part){
  __shared__ unsigned epk[EPC];
  __shared__ int cc[NP];
  __shared__ int cbase[NP];
  __shared__ float bnlds[8][8];
  const int b=blockIdx.x, t=threadIdx.x;
  for (int i=t;i<NP;i+=512) cc[i]=0;
  __syncthreads();
  int base=b*EPC;
  int nb=min(EPC, ET-base);
  for (int k=t;k<nb;k+=512){
    int e=base+k;
    int src,dst;
    if (e<E0){ src=ei[e]; dst=ei[E0+e]; } else { src=dst=e-E0; }
    epk[k]=((unsigned)src<<16)|(unsigned)dst;
    atomicAdd(&cc[dst>>PBITS],1);
  }
  __syncthreads();
  for (int i=t;i<NP;i+=512){
    int c=cc[i];
    cbase[i] = (c>0) ? atomicAdd(&gcur[i], c) : 0;
  }
  __syncthreads();
  for (int i=t;i<NP;i+=512) cc[i]=0;   // reuse as local cursor
  __syncthreads();
  for (int k=t;k<nb;k+=512){
    unsigned w=epk[k];
    int p=(int)((w&0xFFFFu)>>PBITS);
    int lo=atomicAdd(&cc[p],1);
    pedge[p*CAP + cbase[p] + lo]=w;
  }

  if (b<NBP){
    float s[4]={0,0,0,0}, q[4]={0,0,0,0};
    for (int n=b*512+t; n<NN; n+=NBP*512){
      float4 v = reinterpret_cast<const float4*>(x)[n];
      s[0]+=v.x; s[1]+=v.y; s[2]+=v.z; s[3]+=v.w;
      q[0]+=v.x*v.x; q[1]+=v.y*v.y; q[2]+=v.z*v.z; q[3]+=v.w*v.w;
    }
    #pragma unroll
    for (int m=1;m<64;m<<=1){
      #pragma unroll
      for (int i=0;i<4;i++){ s[i]+=__shfl_xor(s[i],m); q[i]+=__shfl_xor(q[i],m); }
    }
    int wid=t>>6, lane=t&63;
    if (lane==0){
      #pragma unroll
      for (int i=0;i<4;i++){ bnlds[wid][i]=s[i]; bnlds[wid][4+i]=q[i]; }
    }
    __syncthreads();
    if (t<8){
      float p=0.f;
      #pragma unroll
      for (int w=0;w<8;w++) p += bnlds[w][t];
      part[b*8+t]=p;
    }
  }
}

// ===== K2: per-partition fine sort -> rbeg/rend + u16 ssrc; block 0: BN finalize + fold =====
// sclsft[0..3]=scale, [4..7]=shift
// fold[0:16) ws1[h*4+i]  fold[16:32) wd1[h*4+i]  fold[32:40) ws3[h*2+i]  fold[40:48) wd3[h*2+i]
__global__ __launch_bounds__(512) void k2_fine(
    const unsigned* __restrict__ pedge, const int* __restrict__ gcur,
    int* __restrict__ rbeg, int* __restrict__ rend, unsigned short* __restrict__ ssrc,
    const float* __restrict__ part, const float* __restrict__ gamma, const float* __restrict__ beta,
    const float* __restrict__ w_e1, const float* __restrict__ as_e1, const float* __restrict__ ad_e1,
    const float* __restrict__ w_d1, const float* __restrict__ as_d1, const float* __restrict__ ad_d1,
    float* __restrict__ sclsft, float* __restrict__ fold){
  const int p=blockIdx.x, t=threadIdx.x;
  int cnt=gcur[p];
  int wbase=p*CAP;
  __shared__ int hist[PSZ], curx[PSZ];
  if (t<PSZ) hist[t]=0;
  __syncthreads();
  for (int i=t;i<cnt;i+=512) atomicAdd(&hist[pedge[wbase+i]&(PSZ-1)],1);
  __syncthreads();
  int o=(t<PSZ)?hist[t]:0;
  __syncthreads();
  int v=o;
  for (int off=1;off<PSZ;off<<=1){
    int tmp=(t>=off&&t<PSZ)?hist[t-off]:0;
    __syncthreads();
    if (t<PSZ){ v+=tmp; hist[t]=v; }
    __syncthreads();
  }
  if (t<PSZ){
    int excl=v-o;
    int d=(p<<PBITS)+t;
    if (d<NN){ rbeg[d]=wbase+excl; rend[d]=wbase+excl+o; }
    curx[t]=wbase+excl;
  }
  __syncthreads();
  for (int i=t;i<cnt;i+=512){
    unsigned w=pedge[wbase+i];
    int pos=atomicAdd(&curx[w&(PSZ-1)],1);
    ssrc[pos]=(unsigned short)(w>>16);
  }

  if (p==0){
    if (t<64){
      int ch=t&7, bslot=t>>3;
      float s=0.f;
      for (int bb=bslot; bb<NBP; bb+=8) s += part[bb*8+ch];
      s += __shfl_xor(s,8); s += __shfl_xor(s,16); s += __shfl_xor(s,32);
      float qv = __shfl(s,(t&3)+4);
      if (t<4){
        float mu  = s*(1.0f/NN);
        float var = qv*(1.0f/NN) - mu*mu;
        float scl = rsqrtf(var + EPS_BN)*gamma[t];
        sclsft[t]   = scl;
        sclsft[4+t] = beta[t] - mu*scl;
      }
    } else if (t<128){
      int u=t-64;
      if (u<32){
        int idx=u&15; int h=idx>>2; int i=idx&3;
        const float* a = (u<16) ? as_e1 : ad_e1;
        float sum=0.f;
        for (int c=0;c<32;c++) sum += w_e1[i*128+h*32+c]*a[h*32+c];
        fold[u]=sum;
      } else if (u<48){
        int idx=u-32; int j=idx&7; int h=j>>1; int i=j&1;
        const float* a = (idx<8) ? as_d1 : ad_d1;
        float sum=0.f;
        for (int c=0;c<32;c++) sum += w_d1[i*128+h*32+c]*a[h*32+c];
        fold[32+idx]=sum;
      }
    }
  }
}

// ===== eagg1: layer-1 (BN + scores recomputed per edge) + fused post1 =====
__global__ __launch_bounds__(256) void eagg1(
    const float* __restrict__ x, const float* __restrict__ sclsft, const float* __restrict__ fold,
    const int* __restrict__ rbeg, const int* __restrict__ rend, const unsigned short* __restrict__ ssrc,
    const float* __restrict__ w_e1, const float* __restrict__ b_e1, const float* __restrict__ w_e3,
    float2* __restrict__ pk2){
  int dst = blockIdx.x*64 + (threadIdx.x>>2);
  int sub = threadIdx.x & 3;
  if (dst >= NN) return;
  float sc[8];
  #pragma unroll
  for (int i=0;i<8;i++) sc[i] = sclsft[i];
  float fs[16];
  #pragma unroll
  for (int i=0;i<16;i++) fs[i] = fold[i];
  float4 xd = reinterpret_cast<const float4*>(x)[dst];
  float xbd[4] = {xd.x*sc[0]+sc[4], xd.y*sc[1]+sc[5], xd.z*sc[2]+sc[6], xd.w*sc[3]+sc[7]};
  float ald[4];
  #pragma unroll
  for (int h=0;h<4;h++)
    ald[h] = xbd[0]*fold[16+h*4+0] + xbd[1]*fold[16+h*4+1]
           + xbd[2]*fold[16+h*4+2] + xbd[3]*fold[16+h*4+3];
  int r0 = rbeg[dst], r1 = rend[dst];
  float sum[4] = {0,0,0,0};
  float acc[4][4] = {{0,0,0,0},{0,0,0,0},{0,0,0,0},{0,0,0,0}};
  for (int i = r0 + sub; i < r1; i += 4){
    int s = ssrc[i];
    float4 xs = reinterpret_cast<const float4*>(x)[s];
    float xb[4] = {xs.x*sc[0]+sc[4], xs.y*sc[1]+sc[5], xs.z*sc[2]+sc[6], xs.w*sc[3]+sc[7]};
    #pragma unroll
    for (int h=0;h<4;h++){
      float a = xb[0]*fs[h*4+0] + xb[1]*fs[h*4+1] + xb[2]*fs[h*4+2] + xb[3]*fs[h*4+3];
      float w = __expf(lrelu(a + ald[h]));
      sum[h] += w;
      acc[h][0] += w*xb[0]; acc[h][1] += w*xb[1]; acc[h][2] += w*xb[2]; acc[h][3] += w*xb[3];
    }
  }
  #pragma unroll
  for (int m=1;m<4;m<<=1){
    #pragma unroll
    for (int h=0;h<4;h++){
      sum[h] += __shfl_xor(sum[h],m);
      #pragma unroll
      for (int c=0;c<4;c++) acc[h][c] += __shfl_xor(acc[h][c],m);
    }
  }
  float G0=acc[0][0], G1=acc[0][1], G2=acc[0][2], G3=acc[0][3], GS=sum[0];
  #pragma unroll
  for (int h=1;h<4;h++){
    if (sub==h){ G0=acc[h][0]; G1=acc[h][1]; G2=acc[h][2]; G3=acc[h][3]; GS=sum[h]; }
  }
  float inv = 1.f/(GS+1e-16f);
  G0*=inv; G1*=inv; G2*=inv; G3*=inv;
  float p0 = 0.f, p1 = 0.f;
  int ob = sub*32;
  #pragma unroll
  for (int q=0;q<8;q++){
    int o = ob + q*4;
    float4 b  = *reinterpret_cast<const float4*>(b_e1 + o);
    float4 w0 = *reinterpret_cast<const float4*>(w_e1 + 0*128 + o);
    float4 w1 = *reinterpret_cast<const float4*>(w_e1 + 1*128 + o);
    float4 w2 = *reinterpret_cast<const float4*>(w_e1 + 2*128 + o);
    float4 w3 = *reinterpret_cast<const float4*>(w_e1 + 3*128 + o);
    float e0 = fmaxf(b.x + G0*w0.x + G1*w1.x + G2*w2.x + G3*w3.x, 0.f);
    float e1 = fmaxf(b.y + G0*w0.y + G1*w1.y + G2*w2.y + G3*w3.y, 0.f);
    float e2 = fmaxf(b.z + G0*w0.z + G1*w1.z + G2*w2.z + G3*w3.z, 0.f);
    float e3 = fmaxf(b.w + G0*w0.w + G1*w1.w + G2*w2.w + G3*w3.w, 0.f);
    float4 wa = *reinterpret_cast<const float4*>(w_e3 + o*2);
    float4 wb = *reinterpret_cast<const float4*>(w_e3 + o*2 + 4);
    p0 += e0*wa.x + e1*wa.z + e2*wb.x + e3*wb.z;
    p1 += e0*wa.y + e1*wa.w + e2*wb.y + e3*wb.w;
  }
  p0 += __shfl_xor(p0,1); p0 += __shfl_xor(p0,2);
  p1 += __shfl_xor(p1,1); p1 += __shfl_xor(p1,2);
  if (sub==0) pk2[dst] = make_float2(p0, p1);
}

// ===== eagg2: layer-2 (scores recomputed from pk2) =====
__global__ __launch_bounds__(256) void eagg2(
    const float2* __restrict__ pk2,
    const int* __restrict__ rbeg, const int* __restrict__ rend, const unsigned short* __restrict__ ssrc,
    const float* __restrict__ as_e3, const float* __restrict__ ad_e3, const float* __restrict__ b_e3,
    float2* __restrict__ lat2){
  int dst = blockIdx.x*64 + (threadIdx.x>>2);
  int sub = threadIdx.x & 3;
  if (dst >= NN) return;
  float as0 = as_e3[0], as1 = as_e3[1];
  float2 pd = pk2[dst];
  float adv = pd.x*ad_e3[0] + pd.y*ad_e3[1];
  int r0 = rbeg[dst], r1 = rend[dst];
  float sum = 0.f, a0 = 0.f, a1 = 0.f;
  for (int i = r0 + sub; i < r1; i += 4){
    int s = ssrc[i];
    float2 p = pk2[s];
    float w = __expf(lrelu(p.x*as0 + p.y*as1 + adv));
    sum += w; a0 += w*p.x; a1 += w*p.y;
  }
  #pragma unroll
  for (int m=1;m<4;m<<=1){
    sum += __shfl_xor(sum,m); a0 += __shfl_xor(a0,m); a1 += __shfl_xor(a1,m);
  }
  if (sub==0){
    float inv = 1.f/(sum+1e-16f);
    lat2[dst] = make_float2(a0*inv + b_e3[0], a1*inv + b_e3[1]);
  }
}

// ===== eagg3: layer-3 (scores recomputed from lat2 via fold) + fused post3 =====
__global__ __launch_bounds__(256) void eagg3(
    const float2* __restrict__ lat2, const float* __restrict__ fold,
    const int* __restrict__ rbeg, const int* __restrict__ rend, const unsigned short* __restrict__ ssrc,
    const float* __restrict__ w_d1, const float* __restrict__ b_d1, const float* __restrict__ w_d3,
    float4* __restrict__ pk4){
  int dst = blockIdx.x*64 + (threadIdx.x>>2);
  int sub = threadIdx.x & 3;
  if (dst >= NN) return;
  float f3[8];
  #pragma unroll
  for (int i=0;i<8;i++) f3[i] = fold[32+i];
  float2 ld = lat2[dst];
  float ald[4];
  #pragma unroll
  for (int h=0;h<4;h++) ald[h] = ld.x*fold[40+h*2+0] + ld.y*fold[40+h*2+1];
  int r0 = rbeg[dst], r1 = rend[dst];
  float sum[4] = {0,0,0,0};
  float acc[4][2] = {{0,0},{0,0},{0,0},{0,0}};
  for (int i = r0 + sub; i < r1; i += 4){
    int s = ssrc[i];
    float2 l = lat2[s];
    #pragma unroll
    for (int h=0;h<4;h++){
      float a = l.x*f3[h*2+0] + l.y*f3[h*2+1];
      float w = __expf(lrelu(a + ald[h]));
      sum[h] += w;
      acc[h][0] += w*l.x; acc[h][1] += w*l.y;
    }
  }
  #pragma unroll
  for (int m=1;m<4;m<<=1){
    #pragma unroll
    for (int h=0;h<4;h++){
      sum[h] += __shfl_xor(sum[h],m);
      acc[h][0] += __shfl_xor(acc[h][0],m);
      acc[h][1] += __shfl_xor(acc[h][1],m);
    }
  }
  float G0=acc[0][0], G1=acc[0][1], GS=sum[0];
  #pragma unroll
  for (int h=1;h<4;h++){
    if (sub==h){ G0=acc[h][0]; G1=acc[h][1]; GS=sum[h]; }
  }
  float inv = 1.f/(GS+1e-16f);
  G0*=inv; G1*=inv;
  float p0=0.f,p1=0.f,p2=0.f,p3=0.f;
  int ob = sub*32;
  #pragma unroll
  for (int q=0;q<8;q++){
    int o = ob + q*4;
    float4 b  = *reinterpret_cast<const float4*>(b_d1 + o);
    float4 w0 = *reinterpret_cast<const float4*>(w_d1 + 0*128 + o);
    float4 w1 = *reinterpret_cast<const float4*>(w_d1 + 1*128 + o);
    float e0 = fmaxf(b.x + G0*w0.x + G1*w1.x, 0.f);
    float e1 = fmaxf(b.y + G0*w0.y + G1*w1.y, 0.f);
    float e2 = fmaxf(b.z + G0*w0.z + G1*w1.z, 0.f);
    float e3 = fmaxf(b.w + G0*w0.w + G1*w1.w, 0.f);
    float4 d0 = *reinterpret_cast<const float4*>(w_d3 + (o+0)*4);
    float4 d1 = *reinterpret_cast<const float4*>(w_d3 + (o+1)*4);
    float4 d2 = *reinterpret_cast<const float4*>(w_d3 + (o+2)*4);
    float4 d3v= *reinterpret_cast<const float4*>(w_d3 + (o+3)*4);
    p0 += e0*d0.x + e1*d1.x + e2*d2.x + e3*d3v.x;
    p1 += e0*d0.y + e1*d1.y + e2*d2.y + e3*d3v.y;
    p2 += e0*d0.z + e1*d1.z + e2*d2.z + e3*d3v.z;
    p3 += e0*d0.w + e1*d1.w + e2*d2.w + e3*d3v.w;
  }
  #pragma unroll
  for (int m=1;m<4;m<<=1){
    p0 += __shfl_xor(p0,m); p1 += __shfl_xor(p1,m);
    p2 += __shfl_xor(p2,m); p3 += __shfl_xor(p3,m);
  }
  if (sub==0) pk4[dst] = make_float4(p0,p1,p2,p3);
}

// ===== eagg4: layer-4 (scores recomputed from pk4) -> output =====
__global__ __launch_bounds__(256) void eagg4(
    const float4* __restrict__ pk4,
    const int* __restrict__ rbeg, const int* __restrict__ rend, const unsigned short* __restrict__ ssrc,
    const float* __restrict__ as_d3, const float* __restrict__ ad_d3, const float* __restrict__ b_d3,
    float* __restrict__ out){
  int dst = blockIdx.x*64 + (threadIdx.x>>2);
  int sub = threadIdx.x & 3;
  if (dst >= NN) return;
  float as0=as_d3[0], as1=as_d3[1], as2=as_d3[2], as3=as_d3[3];
  float4 hd = pk4[dst];
  float adv = hd.x*ad_d3[0] + hd.y*ad_d3[1] + hd.z*ad_d3[2] + hd.w*ad_d3[3];
  int r0 = rbeg[dst], r1 = rend[dst];
  float sum = 0.f, a0=0.f, a1=0.f, a2=0.f, a3=0.f;
  for (int i = r0 + sub; i < r1; i += 4){
    int s = ssrc[i];
    float4 f = pk4[s];
    float w = __expf(lrelu(f.x*as0 + f.y*as1 + f.z*as2 + f.w*as3 + adv));
    sum += w; a0 += w*f.x; a1 += w*f.y; a2 += w*f.z; a3 += w*f.w;
  }
  #pragma unroll
  for (int m=1;m<4;m<<=1){
    sum += __shfl_xor(sum,m);
    a0 += __shfl_xor(a0,m); a1 += __shfl_xor(a1,m);
    a2 += __shfl_xor(a2,m); a3 += __shfl_xor(a3,m);
  }
  if (sub==0){
    float inv = 1.f/(sum+1e-16f);
    reinterpret_cast<float4*>(out)[dst] =
      make_float4(a0*inv+b_d3[0], a1*inv+b_d3[1], a2*inv+b_d3[2], a3*inv+b_d3[3]);
  }
}

// ---------------- launch ----------------
extern "C" void kernel_launch(void* const* d_in, const int* in_sizes, int n_in,
                              void* d_out, int out_size, void* d_ws, size_t ws_size,
                              hipStream_t stream) {
  const float* x     = (const float*)d_in[0];
  const int*   ei    = (const int*)  d_in[1];
  const float* gamma = (const float*)d_in[2];
  const float* beta  = (const float*)d_in[3];
  const float* w_e1  = (const float*)d_in[4];
  const float* as_e1 = (const float*)d_in[5];
  const float* ad_e1 = (const float*)d_in[6];
  const float* b_e1  = (const float*)d_in[7];
  const float* w_e3  = (const float*)d_in[8];
  const float* as_e3 = (const float*)d_in[9];
  const float* ad_e3 = (const float*)d_in[10];
  const float* b_e3  = (const float*)d_in[11];
  const float* w_d1  = (const float*)d_in[12];
  const float* as_d1 = (const float*)d_in[13];
  const float* ad_d1 = (const float*)d_in[14];
  const float* b_d1  = (const float*)d_in[15];
  const float* w_d3  = (const float*)d_in[16];
  const float* as_d3 = (const float*)d_in[17];
  const float* ad_d3 = (const float*)d_in[18];
  const float* b_d3  = (const float*)d_in[19];

  char* ws = (char*)d_ws;
  size_t off = 0;
  auto alloc = [&](size_t bytes)->void*{
    void* p = ws + off;
    off += (bytes + 255) & ~(size_t)255;
    return p;
  };
  unsigned* pedge   = (unsigned*)       alloc((size_t)NP*CAP*4);
  unsigned short* ssrc = (unsigned short*)alloc((size_t)NP*CAP*2);
  int*      gcur    = (int*)            alloc((size_t)NP*4);
  int*      rbeg    = (int*)            alloc((size_t)NN*4);
  int*      rend    = (int*)            alloc((size_t)NN*4);
  float*    part    = (float*)          alloc((size_t)NBP*8*4);
  float*    sclsft  = (float*)          alloc(32);
  float*    fold    = (float*)          alloc(64*4);
  float2*   pk2     = (float2*)         alloc((size_t)NN*8);
  float2*   lat2    = (float2*)         alloc((size_t)NN*8);
  float4*   pk4     = (float4*)         alloc((size_t)NN*16);

  (void)hipMemsetAsync(gcur, 0, (size_t)NP*4, stream);
  k1_stage<<<NCH, 512, 0, stream>>>(ei, x, pedge, gcur, part);
  k2_fine<<<NP, 512, 0, stream>>>(pedge, gcur, rbeg, rend, ssrc, part, gamma, beta,
                                  w_e1, as_e1, ad_e1, w_d1, as_d1, ad_d1, sclsft, fold);

  const int NAGG = (NN + 63)/64;   // 64 dst per 256-thread block (4 lanes/dst)
  eagg1<<<NAGG, 256, 0, stream>>>(x, sclsft, fold, rbeg, rend, ssrc, w_e1, b_e1, w_e3, pk2);
  eagg2<<<NAGG, 256, 0, stream>>>(pk2, rbeg, rend, ssrc, as_e3, ad_e3, b_e3, lat2);
  eagg3<<<NAGG, 256, 0, stream>>>(lat2, fold, rbeg, rend, ssrc, w_d1, b_d1, w_d3, pk4);
  eagg4<<<NAGG, 256, 0, stream>>>(pk4, rbeg, rend, ssrc, as_d3, ad_d3, b_d3, (float*)d_out);
}